// Round 2
// baseline (1287.640 us; speedup 1.0000x reference)
//
#include <hip/hip_runtime.h>
#include <stdint.h>
#include <stddef.h>

#define N_TOK 8192
#define DIM   1024
#define NE    8
#define NF    4096
#define TM    128
#define TN    128
#define BKK   64
#define RCAP  (N_TOK*2 + NE*TM)   /* 17408 padded assignment rows */
#define MAXMT (N_TOK/TM)          /* 64 worst-case m-tiles per expert */

typedef __attribute__((ext_vector_type(8))) short short8;
typedef __attribute__((ext_vector_type(4))) float f32x4;

__device__ __forceinline__ float bf2f(short s){
  unsigned u = ((unsigned)(unsigned short)s) << 16;
  return __builtin_bit_cast(float, u);
}
__device__ __forceinline__ short f2bf(float f){
  unsigned u = __builtin_bit_cast(unsigned, f);
  u += 0x7fffu + ((u >> 16) & 1u);   // RNE (inputs are tame, no NaN)
  return (short)(u >> 16);
}

#define GLD_LDS16(g, l) __builtin_amdgcn_global_load_lds( \
    (const __attribute__((address_space(1))) void*)(g),   \
    (__attribute__((address_space(3))) void*)(l), 16, 0, 0)

// ---------------- gating (pure fp32: selection must match reference) --------
__global__ __launch_bounds__(256) void gate_kernel(
    const float* __restrict__ x, const float* __restrict__ gw,
    int* __restrict__ topi, float* __restrict__ gatev, int* __restrict__ ctrl)
{
  int t = blockIdx.x * 4 + (threadIdx.x >> 6);
  int lane = threadIdx.x & 63;
  const float* xr = x + (size_t)t * DIM;
  float p[NE];
  #pragma unroll
  for (int e = 0; e < NE; e++) p[e] = 0.f;
  for (int i = lane; i < DIM; i += 64){
    float xv = xr[i];
    const float* g = gw + i * NE;
    #pragma unroll
    for (int e = 0; e < NE; e++) p[e] += xv * g[e];
  }
  #pragma unroll
  for (int off = 32; off > 0; off >>= 1){
    #pragma unroll
    for (int e = 0; e < NE; e++) p[e] += __shfl_xor(p[e], off, 64);
  }
  if (lane == 0){
    int i1 = 0; float v1 = p[0];
    #pragma unroll
    for (int e = 1; e < NE; e++) if (p[e] > v1){ v1 = p[e]; i1 = e; }
    int i2 = -1; float v2 = -3.4e38f;
    #pragma unroll
    for (int e = 0; e < NE; e++) if (e != i1 && p[e] > v2){ v2 = p[e]; i2 = e; }
    float ex = expf(v2 - v1);          // v1 >= v2
    float g2 = ex / (1.f + ex);
    float g1 = 1.f - g2;
    topi[t*2]   = i1;  topi[t*2+1]  = i2;
    gatev[t*2]  = g1;  gatev[t*2+1] = g2;
    atomicAdd(&ctrl[i1], 1);
    atomicAdd(&ctrl[i2], 1);
  }
}

// ctrl ints: [0..7]=counts  [8..15]=cursors  [16..23]=offs  [24..31]=caps
__global__ void scan_kernel(int* ctrl){
  if (threadIdx.x == 0){
    int tot = 0;
    for (int e = 0; e < NE; e++){
      int c = ctrl[e];
      int cap = (c + TM - 1) & ~(TM - 1);
      ctrl[16+e] = tot; ctrl[24+e] = cap; tot += cap;
    }
  }
}

__global__ __launch_bounds__(256) void scatter_kernel(
    const int* __restrict__ topi, int* ctrl,
    int* __restrict__ rowTok, int* __restrict__ tok2row)
{
  int t = blockIdx.x * 256 + threadIdx.x;
  #pragma unroll
  for (int k = 0; k < 2; k++){
    int e = topi[t*2 + k];
    int pos = atomicAdd(&ctrl[8+e], 1);
    int r = ctrl[16+e] + pos;
    rowTok[r] = t;
    tok2row[t*2 + k] = r;
  }
}

__global__ void pad_kernel(const int* __restrict__ ctrl, int* __restrict__ rowTok){
  int e = blockIdx.x;
  int cnt = ctrl[e], cap = ctrl[24+e], off = ctrl[16+e];
  for (int i = cnt + threadIdx.x; i < cap; i += blockDim.x)
    rowTok[off + i] = N_TOK;    // sentinel -> zero row of Xb
}

// ---------------- casts -----------------------------------------------------
__global__ __launch_bounds__(256) void cast_x_kernel(
    const float* __restrict__ x, short* __restrict__ xb)
{
  size_t i = ((size_t)blockIdx.x * 256 + threadIdx.x) * 8;
  if (i >= (size_t)(N_TOK + 1) * DIM) return;
  short8 o;
  if (i < (size_t)N_TOK * DIM){
    #pragma unroll
    for (int j = 0; j < 8; j++) o[j] = f2bf(x[i + j]);
  } else {
    #pragma unroll
    for (int j = 0; j < 8; j++) o[j] = 0;
  }
  *(short8*)(xb + i) = o;
}

// src[e][k][n] fp32 -> dst tiles [e][nb][kb] each 128rows(nn) x 64(k) bf16
__global__ __launch_bounds__(256) void cast_w_kernel(
    const float* __restrict__ src, short* __restrict__ dst, int Kd, int Nd)
{
  long tid = (long)blockIdx.x * 256 + threadIdx.x;
  int within = (int)(tid & 1023);
  long tile = tid >> 10;
  int nn = within & 127;          // consecutive threads -> consecutive n (coalesced reads)
  int ko = within >> 7;
  int kt = Kd / 64;
  int kb = (int)(tile % kt); long tmp = tile / kt;
  int nb = (int)(tmp % (Nd / 128)); int e = (int)(tmp / (Nd / 128));
  const float* s = src + (size_t)e * Kd * Nd;
  short8 o;
  #pragma unroll
  for (int j = 0; j < 8; j++){
    int k = kb*64 + ko*8 + j;
    int n = nb*128 + nn;
    o[j] = f2bf(s[(size_t)k * Nd + n]);
  }
  *(short8*)(dst + tile*8192 + nn*64 + ko*8) = o;
}

// ---------------- grouped GEMM 1: H = gelu(Xg @ W1 + b1) --------------------
__global__ __launch_bounds__(256) void ffn1_kernel(
    const short* __restrict__ Xb, const short* __restrict__ W1s,
    const float* __restrict__ b1, const int* __restrict__ ctrl,
    const int* __restrict__ rowTok, short* __restrict__ H)
{
  int e = blockIdx.z, mt = blockIdx.y, nb = blockIdx.x;
  int cap = ctrl[24+e];
  if (mt * TM >= cap) return;
  int rowbase = ctrl[16+e] + mt * TM;

  __shared__ __align__(16) short As[TM][BKK];
  __shared__ __align__(16) short Bs[TN][BKK];

  int tid = threadIdx.x, w = tid >> 6, lane = tid & 63;
  int rsub = lane >> 3, ksub = lane & 7;

  const short* ap[4];
  #pragma unroll
  for (int j = 0; j < 4; j++){
    int g = rowTok[rowbase + w*32 + j*8 + rsub];
    ap[j] = Xb + (size_t)g * DIM + ksub * 8;
  }
  const short* btile = W1s + ((size_t)(e * (NF/TN) + nb) * (DIM/BKK)) * (TN*BKK);
  const short* bp[4];
  #pragma unroll
  for (int j = 0; j < 4; j++) bp[j] = btile + ((w*4 + j)*64 + lane) * 8;

  char* AsB = (char*)As; char* BsB = (char*)Bs;
  int ml = lane & 15, q = lane >> 4;
  int wm = w & 1, wn = w >> 1;
  const short8* Ar = (const short8*)As;
  const short8* Br = (const short8*)Bs;

  f32x4 acc[4][4];
  #pragma unroll
  for (int i = 0; i < 4; i++){
    #pragma unroll
    for (int j = 0; j < 4; j++){ f32x4 z = {0.f,0.f,0.f,0.f}; acc[i][j] = z; }
  }

  for (int kb = 0; kb < DIM/BKK; kb++){
    #pragma unroll
    for (int j = 0; j < 4; j++) GLD_LDS16(ap[j] + kb*BKK, AsB + (w*4 + j)*1024);
    #pragma unroll
    for (int j = 0; j < 4; j++) GLD_LDS16(bp[j] + kb*(TN*BKK), BsB + (w*4 + j)*1024);
    __syncthreads();
    #pragma unroll
    for (int ks = 0; ks < 2; ks++){
      short8 a[4], b[4];
      #pragma unroll
      for (int mi = 0; mi < 4; mi++) a[mi] = Ar[(wm*64 + mi*16 + ml)*8 + ks*4 + q];
      #pragma unroll
      for (int ni = 0; ni < 4; ni++) b[ni] = Br[(wn*64 + ni*16 + ml)*8 + ks*4 + q];
      #pragma unroll
      for (int mi = 0; mi < 4; mi++){
        #pragma unroll
        for (int ni = 0; ni < 4; ni++)
          acc[mi][ni] = __builtin_amdgcn_mfma_f32_16x16x32_bf16(a[mi], b[ni], acc[mi][ni], 0, 0, 0);
      }
    }
    __syncthreads();
  }

  // epilogue: +b1, exact gelu, store bf16 H
  #pragma unroll
  for (int ni = 0; ni < 4; ni++){
    int f = nb*TN + wn*64 + ni*16 + ml;
    float bb = b1[e*NF + f];
    #pragma unroll
    for (int mi = 0; mi < 4; mi++){
      #pragma unroll
      for (int r = 0; r < 4; r++){
        int m = wm*64 + mi*16 + q*4 + r;
        float v = acc[mi][ni][r] + bb;
        float h = 0.5f * v * (1.f + erff(v * 0.70710678118654752f));
        H[(size_t)(rowbase + m) * NF + f] = f2bf(h);
      }
    }
  }
}

// ---------------- grouped GEMM 2: Yp = H @ W2 + b2 --------------------------
__global__ __launch_bounds__(256) void ffn2_kernel(
    const short* __restrict__ H, const short* __restrict__ W2s,
    const float* __restrict__ b2, const int* __restrict__ ctrl,
    short* __restrict__ Yp)
{
  int e = blockIdx.z, mt = blockIdx.y, nb = blockIdx.x;
  int cap = ctrl[24+e];
  if (mt * TM >= cap) return;
  int rowbase = ctrl[16+e] + mt * TM;

  __shared__ __align__(16) short As[TM][BKK];
  __shared__ __align__(16) short Bs[TN][BKK];

  int tid = threadIdx.x, w = tid >> 6, lane = tid & 63;
  int rsub = lane >> 3, ksub = lane & 7;

  const short* ap[4];
  #pragma unroll
  for (int j = 0; j < 4; j++){
    int r = rowbase + w*32 + j*8 + rsub;
    ap[j] = H + (size_t)r * NF + ksub * 8;
  }
  const short* btile = W2s + ((size_t)(e * (DIM/TN) + nb) * (NF/BKK)) * (TN*BKK);
  const short* bp[4];
  #pragma unroll
  for (int j = 0; j < 4; j++) bp[j] = btile + ((w*4 + j)*64 + lane) * 8;

  char* AsB = (char*)As; char* BsB = (char*)Bs;
  int ml = lane & 15, q = lane >> 4;
  int wm = w & 1, wn = w >> 1;
  const short8* Ar = (const short8*)As;
  const short8* Br = (const short8*)Bs;

  f32x4 acc[4][4];
  #pragma unroll
  for (int i = 0; i < 4; i++){
    #pragma unroll
    for (int j = 0; j < 4; j++){ f32x4 z = {0.f,0.f,0.f,0.f}; acc[i][j] = z; }
  }

  for (int kb = 0; kb < NF/BKK; kb++){
    #pragma unroll
    for (int j = 0; j < 4; j++) GLD_LDS16(ap[j] + kb*BKK, AsB + (w*4 + j)*1024);
    #pragma unroll
    for (int j = 0; j < 4; j++) GLD_LDS16(bp[j] + kb*(TN*BKK), BsB + (w*4 + j)*1024);
    __syncthreads();
    #pragma unroll
    for (int ks = 0; ks < 2; ks++){
      short8 a[4], b[4];
      #pragma unroll
      for (int mi = 0; mi < 4; mi++) a[mi] = Ar[(wm*64 + mi*16 + ml)*8 + ks*4 + q];
      #pragma unroll
      for (int ni = 0; ni < 4; ni++) b[ni] = Br[(wn*64 + ni*16 + ml)*8 + ks*4 + q];
      #pragma unroll
      for (int mi = 0; mi < 4; mi++){
        #pragma unroll
        for (int ni = 0; ni < 4; ni++)
          acc[mi][ni] = __builtin_amdgcn_mfma_f32_16x16x32_bf16(a[mi], b[ni], acc[mi][ni], 0, 0, 0);
      }
    }
    __syncthreads();
  }

  #pragma unroll
  for (int ni = 0; ni < 4; ni++){
    int d = nb*TN + wn*64 + ni*16 + ml;
    float bb = b2[e*DIM + d];
    #pragma unroll
    for (int mi = 0; mi < 4; mi++){
      #pragma unroll
      for (int r = 0; r < 4; r++){
        int m = wm*64 + mi*16 + q*4 + r;
        Yp[(size_t)(rowbase + m) * DIM + d] = f2bf(acc[mi][ni][r] + bb);
      }
    }
  }
}

// ---------------- combine: out = g0*y0 + g1*y1 ------------------------------
__global__ __launch_bounds__(256) void combine_kernel(
    const short* __restrict__ Yp, const int* __restrict__ tok2row,
    const float* __restrict__ gatev, float* __restrict__ out)
{
  int idx = blockIdx.x * 256 + threadIdx.x;   // over N_TOK * (DIM/8)
  int t = idx >> 7, d8 = idx & 127;
  int r0 = tok2row[t*2], r1 = tok2row[t*2 + 1];
  float g0 = gatev[t*2], g1 = gatev[t*2 + 1];
  short8 y0 = *(const short8*)(Yp + (size_t)r0 * DIM + d8*8);
  short8 y1 = *(const short8*)(Yp + (size_t)r1 * DIM + d8*8);
  float o[8];
  #pragma unroll
  for (int j = 0; j < 8; j++) o[j] = g0 * bf2f(y0[j]) + g1 * bf2f(y1[j]);
  f32x4 v0 = {o[0], o[1], o[2], o[3]};
  f32x4 v1 = {o[4], o[5], o[6], o[7]};
  f32x4* dst = (f32x4*)(out + (size_t)t * DIM + d8*8);
  dst[0] = v0; dst[1] = v1;
}

// ---------------- launch ----------------------------------------------------
extern "C" void kernel_launch(void* const* d_in, const int* in_sizes, int n_in,
                              void* d_out, int out_size, void* d_ws, size_t ws_size,
                              hipStream_t stream)
{
  const float* x  = (const float*)d_in[0];
  const float* gw = (const float*)d_in[1];
  const float* w1 = (const float*)d_in[2];
  const float* b1 = (const float*)d_in[3];
  const float* w2 = (const float*)d_in[4];
  const float* b2 = (const float*)d_in[5];
  float* out = (float*)d_out;

  char* ws = (char*)d_ws;
  size_t o = 0;
  int*   ctrl    = (int*)(ws + o); o += 256;
  int*   topi    = (int*)(ws + o); o += (size_t)N_TOK*2*4;
  float* gatev   = (float*)(ws + o); o += (size_t)N_TOK*2*4;
  int*   rowTok  = (int*)(ws + o); o += (size_t)RCAP*4;
  int*   tok2row = (int*)(ws + o); o += (size_t)N_TOK*2*4;
  o = (o + 255) & ~(size_t)255;
  short* Xb  = (short*)(ws + o); o += (size_t)(N_TOK + 1)*DIM*2;
  short* W1s = (short*)(ws + o); o += (size_t)NE*DIM*NF*2;
  short* W2s = (short*)(ws + o); o += (size_t)NE*NF*DIM*2;
  short* H   = (short*)(ws + o); o += (size_t)RCAP*NF*2;
  short* Yp  = (short*)(ws + o); o += (size_t)RCAP*DIM*2;
  (void)in_sizes; (void)n_in; (void)out_size;

  // Workspace guard: if ws_size is insufficient, bail out cleanly (output
  // stays poisoned -> harness reports a plain correctness failure, which
  // tells us ws_size is the constraint; avoids OOB writes crashing the box).
  if (o > ws_size) return;

  hipMemsetAsync(ctrl, 0, 256, stream);
  gate_kernel<<<N_TOK/4, 256, 0, stream>>>(x, gw, topi, gatev, ctrl);
  scan_kernel<<<1, 64, 0, stream>>>(ctrl);
  scatter_kernel<<<N_TOK/256, 256, 0, stream>>>(topi, ctrl, rowTok, tok2row);
  pad_kernel<<<NE, 128, 0, stream>>>(ctrl, rowTok);
  cast_x_kernel<<<((N_TOK + 1)*DIM/8 + 255)/256, 256, 0, stream>>>(x, Xb);
  cast_w_kernel<<<NE*(NF/128)*(DIM/64)*1024/256, 256, 0, stream>>>(w1, W1s, DIM, NF);
  cast_w_kernel<<<NE*(DIM/128)*(NF/64)*1024/256, 256, 0, stream>>>(w2, W2s, NF, DIM);
  ffn1_kernel<<<dim3(NF/TN, MAXMT, NE), 256, 0, stream>>>(Xb, W1s, b1, ctrl, rowTok, H);
  ffn2_kernel<<<dim3(DIM/TN, MAXMT, NE), 256, 0, stream>>>(H, W2s, b2, ctrl, Yp);
  combine_kernel<<<N_TOK*(DIM/8)/256, 256, 0, stream>>>(Yp, tok2row, gatev, out);
}

// Round 3
// 1124.353 us; speedup vs baseline: 1.1452x; 1.1452x over previous
//
#include <hip/hip_runtime.h>
#include <stdint.h>
#include <stddef.h>

#define N_TOK 8192
#define DIM   1024
#define NE    8
#define NF    4096
#define TM    128
#define TN    128
#define BKK   64
#define RCAP  (N_TOK*2 + NE*TM)   /* 17408 padded assignment rows */
#define MAXMT (N_TOK/TM)          /* 64 worst-case m-tiles per expert */

typedef __attribute__((ext_vector_type(8))) short short8;
typedef __attribute__((ext_vector_type(4))) float f32x4;

__device__ __forceinline__ float bf2f(short s){
  unsigned u = ((unsigned)(unsigned short)s) << 16;
  return __builtin_bit_cast(float, u);
}
__device__ __forceinline__ short f2bf(float f){
  unsigned u = __builtin_bit_cast(unsigned, f);
  u += 0x7fffu + ((u >> 16) & 1u);   // RNE (inputs are tame, no NaN)
  return (short)(u >> 16);
}

#define GLD_LDS16(g, l) __builtin_amdgcn_global_load_lds( \
    (const __attribute__((address_space(1))) void*)(g),   \
    (__attribute__((address_space(3))) void*)(l), 16, 0, 0)

// ---------------- gating (pure fp32: selection must match reference) --------
__global__ __launch_bounds__(256) void gate_kernel(
    const float* __restrict__ x, const float* __restrict__ gw,
    int* __restrict__ topi, float* __restrict__ gatev, int* __restrict__ ctrl)
{
  int t = blockIdx.x * 4 + (threadIdx.x >> 6);
  int lane = threadIdx.x & 63;
  const float* xr = x + (size_t)t * DIM;
  float p[NE];
  #pragma unroll
  for (int e = 0; e < NE; e++) p[e] = 0.f;
  for (int i = lane; i < DIM; i += 64){
    float xv = xr[i];
    const float* g = gw + i * NE;
    #pragma unroll
    for (int e = 0; e < NE; e++) p[e] += xv * g[e];
  }
  #pragma unroll
  for (int off = 32; off > 0; off >>= 1){
    #pragma unroll
    for (int e = 0; e < NE; e++) p[e] += __shfl_xor(p[e], off, 64);
  }
  if (lane == 0){
    int i1 = 0; float v1 = p[0];
    #pragma unroll
    for (int e = 1; e < NE; e++) if (p[e] > v1){ v1 = p[e]; i1 = e; }
    int i2 = -1; float v2 = -3.4e38f;
    #pragma unroll
    for (int e = 0; e < NE; e++) if (e != i1 && p[e] > v2){ v2 = p[e]; i2 = e; }
    float ex = expf(v2 - v1);          // v1 >= v2
    float g2 = ex / (1.f + ex);
    float g1 = 1.f - g2;
    topi[t*2]   = i1;  topi[t*2+1]  = i2;
    gatev[t*2]  = g1;  gatev[t*2+1] = g2;
    atomicAdd(&ctrl[i1], 1);
    atomicAdd(&ctrl[i2], 1);
  }
}

// ctrl ints: [0..7]=counts  [8..15]=cursors  [16..23]=offs  [24..31]=caps
__global__ void scan_kernel(int* ctrl){
  if (threadIdx.x == 0){
    int tot = 0;
    for (int e = 0; e < NE; e++){
      int c = ctrl[e];
      int cap = (c + TM - 1) & ~(TM - 1);
      ctrl[16+e] = tot; ctrl[24+e] = cap; tot += cap;
    }
  }
}

__global__ __launch_bounds__(256) void scatter_kernel(
    const int* __restrict__ topi, int* ctrl,
    int* __restrict__ rowTok, int* __restrict__ tok2row)
{
  int t = blockIdx.x * 256 + threadIdx.x;
  #pragma unroll
  for (int k = 0; k < 2; k++){
    int e = topi[t*2 + k];
    int pos = atomicAdd(&ctrl[8+e], 1);
    int r = ctrl[16+e] + pos;
    rowTok[r] = t;
    tok2row[t*2 + k] = r;
  }
}

__global__ void pad_kernel(const int* __restrict__ ctrl, int* __restrict__ rowTok){
  int e = blockIdx.x;
  int cnt = ctrl[e], cap = ctrl[24+e], off = ctrl[16+e];
  for (int i = cnt + threadIdx.x; i < cap; i += blockDim.x)
    rowTok[off + i] = N_TOK;    // sentinel -> zero row of Xb
}

// ---------------- casts -----------------------------------------------------
__global__ __launch_bounds__(256) void cast_x_kernel(
    const float* __restrict__ x, short* __restrict__ xb)
{
  size_t i = ((size_t)blockIdx.x * 256 + threadIdx.x) * 8;
  if (i >= (size_t)(N_TOK + 1) * DIM) return;
  short8 o;
  if (i < (size_t)N_TOK * DIM){
    #pragma unroll
    for (int j = 0; j < 8; j++) o[j] = f2bf(x[i + j]);
  } else {
    #pragma unroll
    for (int j = 0; j < 8; j++) o[j] = 0;
  }
  *(short8*)(xb + i) = o;
}

// src[e][k][n] fp32 -> dst[e][n][k] bf16, LDS-tiled 64x64 transpose.
// Both global sides fully coalesced; LDS padded to 65 (2-way max, free).
__global__ __launch_bounds__(256) void transpose_cast_kernel(
    const float* __restrict__ src, short* __restrict__ dst, int Kd, int Nd)
{
  __shared__ float Ls[64][65];
  int e = blockIdx.z;
  int k0 = blockIdx.y * 64, n0 = blockIdx.x * 64;
  const float* s = src + (size_t)e * Kd * Nd;
  short*       d = dst + (size_t)e * Kd * Nd;
  int t = threadIdx.x;
  int kr = t >> 4, nc = (t & 15) * 4;      // read: rows along k, 16B along n
  #pragma unroll
  for (int rr = 0; rr < 4; rr++){
    int k = rr*16 + kr;
    f32x4 v = *(const f32x4*)(s + (size_t)(k0 + k) * Nd + n0 + nc);
    Ls[k][nc+0] = v[0]; Ls[k][nc+1] = v[1];
    Ls[k][nc+2] = v[2]; Ls[k][nc+3] = v[3];
  }
  __syncthreads();
  int nr = t >> 2, kc = (t & 3) * 16;      // write: rows along n, 32B along k
  short o[16];
  #pragma unroll
  for (int i = 0; i < 16; i++) o[i] = f2bf(Ls[kc + i][nr]);
  short* dp = d + (size_t)(n0 + nr) * Kd + k0 + kc;
  *(short8*)(dp)     = *(short8*)&o[0];
  *(short8*)(dp + 8) = *(short8*)&o[8];
}

// ---------------- grouped GEMM 1: H = gelu(Xg @ W1 + b1) --------------------
// LDS XOR swizzle: physical 16B chunk p of row r holds logical chunk p^(r&7).
__global__ __launch_bounds__(256) void ffn1_kernel(
    const short* __restrict__ Xb, const short* __restrict__ W1t,
    const float* __restrict__ b1, const int* __restrict__ ctrl,
    const int* __restrict__ rowTok, short* __restrict__ H)
{
  int e = blockIdx.z, mt = blockIdx.y, nb = blockIdx.x;
  int cap = ctrl[24+e];
  if (mt * TM >= cap) return;
  int rowbase = ctrl[16+e] + mt * TM;

  __shared__ __align__(16) short As[TM][BKK];
  __shared__ __align__(16) short Bs[TN][BKK];

  int tid = threadIdx.x, w = tid >> 6, lane = tid & 63;
  int rsub = lane >> 3, ksub = lane & 7;
  int sw = (ksub ^ rsub) * 8;              // swizzled source chunk (shorts)

  const short* ap[4];
  #pragma unroll
  for (int j = 0; j < 4; j++){
    int g = rowTok[rowbase + w*32 + j*8 + rsub];
    ap[j] = Xb + (size_t)g * DIM + sw;
  }
  const short* bbase = W1t + ((size_t)e * NF + (size_t)nb * TN) * DIM;  // [n][k]
  const short* bp[4];
  #pragma unroll
  for (int j = 0; j < 4; j++)
    bp[j] = bbase + (size_t)((w*4 + j)*8 + rsub) * DIM + sw;

  char* AsB = (char*)As; char* BsB = (char*)Bs;
  int ml = lane & 15, q = lane >> 4;
  int wm = w & 1, wn = w >> 1;
  int mx = ml & 7;                         // row&7 for fragment rows
  const short8* Ar = (const short8*)As;
  const short8* Br = (const short8*)Bs;

  f32x4 acc[4][4];
  #pragma unroll
  for (int i = 0; i < 4; i++){
    #pragma unroll
    for (int j = 0; j < 4; j++){ f32x4 z = {0.f,0.f,0.f,0.f}; acc[i][j] = z; }
  }

  for (int kb = 0; kb < DIM/BKK; kb++){
    #pragma unroll
    for (int j = 0; j < 4; j++) GLD_LDS16(ap[j] + kb*BKK, AsB + (w*4 + j)*1024);
    #pragma unroll
    for (int j = 0; j < 4; j++) GLD_LDS16(bp[j] + kb*BKK, BsB + (w*4 + j)*1024);
    __syncthreads();
    #pragma unroll
    for (int ks = 0; ks < 2; ks++){
      int c = (ks*4 + q) ^ mx;             // swizzled chunk for this lane
      short8 a[4], b[4];
      #pragma unroll
      for (int mi = 0; mi < 4; mi++) a[mi] = Ar[(wm*64 + mi*16 + ml)*8 + c];
      #pragma unroll
      for (int ni = 0; ni < 4; ni++) b[ni] = Br[(wn*64 + ni*16 + ml)*8 + c];
      #pragma unroll
      for (int mi = 0; mi < 4; mi++){
        #pragma unroll
        for (int ni = 0; ni < 4; ni++)
          acc[mi][ni] = __builtin_amdgcn_mfma_f32_16x16x32_bf16(a[mi], b[ni], acc[mi][ni], 0, 0, 0);
      }
    }
    __syncthreads();
  }

  // epilogue: +b1, exact gelu, store bf16 H
  #pragma unroll
  for (int ni = 0; ni < 4; ni++){
    int f = nb*TN + wn*64 + ni*16 + ml;
    float bb = b1[e*NF + f];
    #pragma unroll
    for (int mi = 0; mi < 4; mi++){
      #pragma unroll
      for (int r = 0; r < 4; r++){
        int m = wm*64 + mi*16 + q*4 + r;
        float v = acc[mi][ni][r] + bb;
        float h = 0.5f * v * (1.f + erff(v * 0.70710678118654752f));
        H[(size_t)(rowbase + m) * NF + f] = f2bf(h);
      }
    }
  }
}

// ---------------- grouped GEMM 2: Yp = H @ W2 + b2 --------------------------
__global__ __launch_bounds__(256) void ffn2_kernel(
    const short* __restrict__ H, const short* __restrict__ W2t,
    const float* __restrict__ b2, const int* __restrict__ ctrl,
    short* __restrict__ Yp)
{
  int e = blockIdx.z, mt = blockIdx.y, nb = blockIdx.x;
  int cap = ctrl[24+e];
  if (mt * TM >= cap) return;
  int rowbase = ctrl[16+e] + mt * TM;

  __shared__ __align__(16) short As[TM][BKK];
  __shared__ __align__(16) short Bs[TN][BKK];

  int tid = threadIdx.x, w = tid >> 6, lane = tid & 63;
  int rsub = lane >> 3, ksub = lane & 7;
  int sw = (ksub ^ rsub) * 8;

  const short* ap[4];
  #pragma unroll
  for (int j = 0; j < 4; j++){
    int r = rowbase + w*32 + j*8 + rsub;
    ap[j] = H + (size_t)r * NF + sw;
  }
  const short* bbase = W2t + ((size_t)e * DIM + (size_t)nb * TN) * NF;  // [n][k]
  const short* bp[4];
  #pragma unroll
  for (int j = 0; j < 4; j++)
    bp[j] = bbase + (size_t)((w*4 + j)*8 + rsub) * NF + sw;

  char* AsB = (char*)As; char* BsB = (char*)Bs;
  int ml = lane & 15, q = lane >> 4;
  int wm = w & 1, wn = w >> 1;
  int mx = ml & 7;
  const short8* Ar = (const short8*)As;
  const short8* Br = (const short8*)Bs;

  f32x4 acc[4][4];
  #pragma unroll
  for (int i = 0; i < 4; i++){
    #pragma unroll
    for (int j = 0; j < 4; j++){ f32x4 z = {0.f,0.f,0.f,0.f}; acc[i][j] = z; }
  }

  for (int kb = 0; kb < NF/BKK; kb++){
    #pragma unroll
    for (int j = 0; j < 4; j++) GLD_LDS16(ap[j] + kb*BKK, AsB + (w*4 + j)*1024);
    #pragma unroll
    for (int j = 0; j < 4; j++) GLD_LDS16(bp[j] + kb*BKK, BsB + (w*4 + j)*1024);
    __syncthreads();
    #pragma unroll
    for (int ks = 0; ks < 2; ks++){
      int c = (ks*4 + q) ^ mx;
      short8 a[4], b[4];
      #pragma unroll
      for (int mi = 0; mi < 4; mi++) a[mi] = Ar[(wm*64 + mi*16 + ml)*8 + c];
      #pragma unroll
      for (int ni = 0; ni < 4; ni++) b[ni] = Br[(wn*64 + ni*16 + ml)*8 + c];
      #pragma unroll
      for (int mi = 0; mi < 4; mi++){
        #pragma unroll
        for (int ni = 0; ni < 4; ni++)
          acc[mi][ni] = __builtin_amdgcn_mfma_f32_16x16x32_bf16(a[mi], b[ni], acc[mi][ni], 0, 0, 0);
      }
    }
    __syncthreads();
  }

  #pragma unroll
  for (int ni = 0; ni < 4; ni++){
    int d = nb*TN + wn*64 + ni*16 + ml;
    float bb = b2[e*DIM + d];
    #pragma unroll
    for (int mi = 0; mi < 4; mi++){
      #pragma unroll
      for (int r = 0; r < 4; r++){
        int m = wm*64 + mi*16 + q*4 + r;
        Yp[(size_t)(rowbase + m) * DIM + d] = f2bf(acc[mi][ni][r] + bb);
      }
    }
  }
}

// ---------------- combine: out = g0*y0 + g1*y1 ------------------------------
__global__ __launch_bounds__(256) void combine_kernel(
    const short* __restrict__ Yp, const int* __restrict__ tok2row,
    const float* __restrict__ gatev, float* __restrict__ out)
{
  int idx = blockIdx.x * 256 + threadIdx.x;   // over N_TOK * (DIM/8)
  int t = idx >> 7, d8 = idx & 127;
  int r0 = tok2row[t*2], r1 = tok2row[t*2 + 1];
  float g0 = gatev[t*2], g1 = gatev[t*2 + 1];
  short8 y0 = *(const short8*)(Yp + (size_t)r0 * DIM + d8*8);
  short8 y1 = *(const short8*)(Yp + (size_t)r1 * DIM + d8*8);
  float o[8];
  #pragma unroll
  for (int j = 0; j < 8; j++) o[j] = g0 * bf2f(y0[j]) + g1 * bf2f(y1[j]);
  f32x4 v0 = {o[0], o[1], o[2], o[3]};
  f32x4 v1 = {o[4], o[5], o[6], o[7]};
  f32x4* dst = (f32x4*)(out + (size_t)t * DIM + d8*8);
  dst[0] = v0; dst[1] = v1;
}

// ---------------- launch ----------------------------------------------------
extern "C" void kernel_launch(void* const* d_in, const int* in_sizes, int n_in,
                              void* d_out, int out_size, void* d_ws, size_t ws_size,
                              hipStream_t stream)
{
  const float* x  = (const float*)d_in[0];
  const float* gw = (const float*)d_in[1];
  const float* w1 = (const float*)d_in[2];
  const float* b1 = (const float*)d_in[3];
  const float* w2 = (const float*)d_in[4];
  const float* b2 = (const float*)d_in[5];
  float* out = (float*)d_out;

  char* ws = (char*)d_ws;
  size_t o = 0;
  int*   ctrl    = (int*)(ws + o); o += 256;
  int*   topi    = (int*)(ws + o); o += (size_t)N_TOK*2*4;
  float* gatev   = (float*)(ws + o); o += (size_t)N_TOK*2*4;
  int*   rowTok  = (int*)(ws + o); o += (size_t)RCAP*4;
  int*   tok2row = (int*)(ws + o); o += (size_t)N_TOK*2*4;
  o = (o + 255) & ~(size_t)255;
  short* Xb  = (short*)(ws + o); o += (size_t)(N_TOK + 1)*DIM*2;
  short* W1t = (short*)(ws + o); o += (size_t)NE*DIM*NF*2;
  short* W2t = (short*)(ws + o); o += (size_t)NE*NF*DIM*2;
  short* H   = (short*)(ws + o); o += (size_t)RCAP*NF*2;
  short* Yp  = (short*)(ws + o); o += (size_t)RCAP*DIM*2;
  (void)in_sizes; (void)n_in; (void)out_size;

  if (o > ws_size) return;   // clean bail (diagnostic) instead of OOB crash

  hipMemsetAsync(ctrl, 0, 256, stream);
  gate_kernel<<<N_TOK/4, 256, 0, stream>>>(x, gw, topi, gatev, ctrl);
  scan_kernel<<<1, 64, 0, stream>>>(ctrl);
  scatter_kernel<<<N_TOK/256, 256, 0, stream>>>(topi, ctrl, rowTok, tok2row);
  pad_kernel<<<NE, 128, 0, stream>>>(ctrl, rowTok);
  cast_x_kernel<<<((N_TOK + 1)*DIM/8 + 255)/256, 256, 0, stream>>>(x, Xb);
  transpose_cast_kernel<<<dim3(NF/64, DIM/64, NE), 256, 0, stream>>>(w1, W1t, DIM, NF);
  transpose_cast_kernel<<<dim3(DIM/64, NF/64, NE), 256, 0, stream>>>(w2, W2t, NF, DIM);
  ffn1_kernel<<<dim3(NF/TN, MAXMT, NE), 256, 0, stream>>>(Xb, W1t, b1, ctrl, rowTok, H);
  ffn2_kernel<<<dim3(DIM/TN, MAXMT, NE), 256, 0, stream>>>(H, W2t, b2, ctrl, Yp);
  combine_kernel<<<N_TOK*(DIM/8)/256, 256, 0, stream>>>(Yp, tok2row, gatev, out);
}